// Round 4
// baseline (306.494 us; speedup 1.0000x reference)
//
#include <hip/hip_runtime.h>

// ---------------------------------------------------------------------------
// MultiHeadAttention (B=2, S=2048, D=1024, H=16, dk=64) on gfx950
// R8: flash_attn rewritten BARRIER-FREE: no K/V LDS staging at all — MFMA
// fragments are loaded directly from global (L2-resident: 512 KB KV/head,
// 4 heads/XCD via swizzle). 4-wave blocks (2 q-groups x 2 kv-halves),
// grid 1024, LDS = 16 KB end-merge only, 16 waves/CU free-running.
// Mask precomputed into a f32 additive table by cvt_all (log2 domain).
// Softmax fully in-register: p seeded from mask table, bare exp2,
// cvt-pack + permlane32_swap, scalar lsum (+shfl_xor 32).
// qkv_fused / out_proj reverted to R6 form (only Q scale = 0.125*log2e kept).
// ---------------------------------------------------------------------------

typedef __bf16 bf16_8 __attribute__((ext_vector_type(8)));
typedef float  f32x4  __attribute__((ext_vector_type(4)));
typedef float  f32x16 __attribute__((ext_vector_type(16)));
typedef unsigned int u32x4 __attribute__((ext_vector_type(4)));

#define MFMA16(a, b, c) __builtin_amdgcn_mfma_f32_16x16x32_bf16((a), (b), (c), 0, 0, 0)
#define MFMA32(a, b, c) __builtin_amdgcn_mfma_f32_32x32x16_bf16((a), (b), (c), 0, 0, 0)

__device__ __forceinline__ void async_ld16(const void* g, void* l) {
  __builtin_amdgcn_global_load_lds(
      (__attribute__((address_space(1))) void*)g,
      (__attribute__((address_space(3))) void*)l, 16, 0, 0);
}

// ---------------------------------------------------------------------------
// 128x128 GEMM core (m97 structure), BK=32, A [MxK] rm, BT [NxK] rm.
// ---------------------------------------------------------------------------
__device__ __forceinline__ void gemm_core_128(
    const __bf16* __restrict__ A, const __bf16* __restrict__ BT, int K,
    int tm, int tn, __bf16* At, __bf16* Bt, f32x4 acc[4][4]) {
  const int tid  = threadIdx.x;
  const int lane = tid & 63;
  const int w    = tid >> 6;
  const int quad = lane >> 4;
  const int c16  = lane & 15;
  const int wm = w >> 1, wn = w & 1;

  const int ch0  = w * 2;
  const int row0 = ch0 * 16 + (lane >> 2);
  const int col0 = (lane & 3) * 8;
  const __bf16* Ag = A  + (size_t)(tm + row0) * K + col0;
  const __bf16* Bg = BT + (size_t)(tn + row0) * K + col0;
  __bf16* Al = At + ch0 * 512;
  __bf16* Bl = Bt + ch0 * 512;
  const size_t rowK16 = (size_t)16 * K;

  for (int kt = 0; kt < K; kt += 32) {
    async_ld16(Ag + kt,          Al);
    async_ld16(Ag + rowK16 + kt, Al + 512);
    async_ld16(Bg + kt,          Bl);
    async_ld16(Bg + rowK16 + kt, Bl + 512);
    __syncthreads();

    bf16_8 af[4], bfr[4];
#pragma unroll
    for (int mi = 0; mi < 4; ++mi)
      af[mi] = *(const bf16_8*)(At + (wm * 64 + mi * 16 + c16) * 32 + quad * 8);
#pragma unroll
    for (int ni = 0; ni < 4; ++ni)
      bfr[ni] = *(const bf16_8*)(Bt + (wn * 64 + ni * 16 + c16) * 32 + quad * 8);
#pragma unroll
    for (int mi = 0; mi < 4; ++mi)
#pragma unroll
      for (int ni = 0; ni < 4; ++ni)
        acc[mi][ni] = MFMA16(af[mi], bfr[ni], acc[mi][ni]);
    __syncthreads();
  }
}

// ---------------------------------------------------------------------------
// Fused QKV projection. grid = (256,1,3). V produced transposed [B,H,64,S].
// Q output pre-scaled by 0.125*log2e (flash softmax works in log2 domain).
// ---------------------------------------------------------------------------
__global__ __launch_bounds__(256)
void qkv_fused(const __bf16* __restrict__ xq, const __bf16* __restrict__ xk,
               const __bf16* __restrict__ xv,
               const __bf16* __restrict__ wq, const __bf16* __restrict__ wk,
               const __bf16* __restrict__ wv,
               const float* __restrict__ bq, const float* __restrict__ bk,
               const float* __restrict__ bv,
               __bf16* __restrict__ Qo, __bf16* __restrict__ Ko,
               __bf16* __restrict__ Vo) {
  __shared__ __bf16 At[128 * 32];
  __shared__ __bf16 Bt[128 * 32];
  const int z  = blockIdx.z;
  const int bx = blockIdx.x;
  const __bf16 *A, *BT;
  const float* bias;
  int tm, tn;
  if (z == 2) {        // V^T: M=1024 feats, N=4096 tokens
    A = wv; BT = xv; bias = bv;
    tm = (bx >> 5) * 128; tn = (bx & 31) * 128;
  } else if (z == 1) {
    A = xk; BT = wk; bias = bk;
    tm = (bx >> 3) * 128; tn = (bx & 7) * 128;
  } else {
    A = xq; BT = wq; bias = bq;
    tm = (bx >> 3) * 128; tn = (bx & 7) * 128;
  }

  f32x4 acc[4][4];
  const f32x4 zero4 = {0.f, 0.f, 0.f, 0.f};
#pragma unroll
  for (int i = 0; i < 4; ++i)
#pragma unroll
    for (int j = 0; j < 4; ++j) acc[i][j] = zero4;

  gemm_core_128(A, BT, 1024, tm, tn, At, Bt, acc);

  const int lane = threadIdx.x & 63;
  const int w    = threadIdx.x >> 6;
  const int quad = lane >> 4, c16 = lane & 15;
  const int wm = w >> 1, wn = w & 1;

  if (z == 2) {
#pragma unroll
    for (int mi = 0; mi < 4; ++mi) {
#pragma unroll
      for (int ni = 0; ni < 4; ++ni) {
        const int n  = tn + wn * 64 + ni * 16 + c16;  // token
        const int bb = n >> 11, s = n & 2047;
#pragma unroll
        for (int r = 0; r < 4; ++r) {
          const int m  = tm + wm * 64 + mi * 16 + quad * 4 + r;  // feature
          const int hh = m >> 6, d = m & 63;
          Vo[(((size_t)(bb * 16 + hh) * 64 + d) << 11) + s] =
              (__bf16)(acc[mi][ni][r] + bias[m]);
        }
      }
    }
  } else {
    __bf16* Out = (z == 1) ? Ko : Qo;
    const float scale = (z == 0) ? 0.1803368801f : 1.0f;  // 0.125 * log2(e)
#pragma unroll
    for (int mi = 0; mi < 4; ++mi) {
#pragma unroll
      for (int ni = 0; ni < 4; ++ni) {
        const int n  = tn + wn * 64 + ni * 16 + c16;  // feature
        const int hh = n >> 6, d = n & 63;
        const float bn = bias[n];
#pragma unroll
        for (int r = 0; r < 4; ++r) {
          const int m  = tm + wm * 64 + mi * 16 + quad * 4 + r;  // token
          const int bb = m >> 11, s = m & 2047;
          Out[(((size_t)(bb * 16 + hh) * 2048 + s) << 6) + d] =
              (__bf16)((acc[mi][ni][r] + bn) * scale);
        }
      }
    }
  }
}

// ---------------------------------------------------------------------------
// Output projection, 64x128 tile -> 512 blocks (2 blocks/CU).
// ---------------------------------------------------------------------------
__global__ __launch_bounds__(256)
void out_proj(const __bf16* __restrict__ ctx, const __bf16* __restrict__ wo,
              const float* __restrict__ bo, float* __restrict__ out) {
  __shared__ __bf16 At[64 * 32];
  __shared__ __bf16 Bt[128 * 32];
  const int bx = blockIdx.x;
  const int tm = (bx >> 3) * 64, tn = (bx & 7) * 128;

  const int tid  = threadIdx.x;
  const int lane = tid & 63, w = tid >> 6;
  const int quad = lane >> 4, c16 = lane & 15;
  const int wm = w >> 1, wn = w & 1;

  const int row0 = lane >> 2, col0 = (lane & 3) * 8;
  const __bf16* Ag = ctx + (size_t)(tm + w * 16 + row0) * 1024 + col0;
  const __bf16* Bg = wo  + (size_t)(tn + w * 32 + row0) * 1024 + col0;
  __bf16* Al = At + w * 512;
  __bf16* Bl = Bt + w * 1024;

  f32x4 acc[2][4];
  const f32x4 zero4 = {0.f, 0.f, 0.f, 0.f};
#pragma unroll
  for (int i = 0; i < 2; ++i)
#pragma unroll
    for (int j = 0; j < 4; ++j) acc[i][j] = zero4;

  for (int kt = 0; kt < 1024; kt += 32) {
    async_ld16(Ag + kt, Al);
    async_ld16(Bg + kt, Bl);
    async_ld16(Bg + 16 * 1024 + kt, Bl + 512);
    __syncthreads();

    bf16_8 af[2], bfr[4];
#pragma unroll
    for (int mi = 0; mi < 2; ++mi)
      af[mi] = *(const bf16_8*)(At + (wm * 32 + mi * 16 + c16) * 32 + quad * 8);
#pragma unroll
    for (int ni = 0; ni < 4; ++ni)
      bfr[ni] = *(const bf16_8*)(Bt + (wn * 64 + ni * 16 + c16) * 32 + quad * 8);
#pragma unroll
    for (int mi = 0; mi < 2; ++mi)
#pragma unroll
      for (int ni = 0; ni < 4; ++ni)
        acc[mi][ni] = MFMA16(af[mi], bfr[ni], acc[mi][ni]);
    __syncthreads();
  }

#pragma unroll
  for (int mi = 0; mi < 2; ++mi) {
#pragma unroll
    for (int ni = 0; ni < 4; ++ni) {
      const int n = tn + wn * 64 + ni * 16 + c16;
      const float bn = bo[n];
#pragma unroll
      for (int r = 0; r < 4; ++r) {
        const int m = tm + wm * 32 + mi * 16 + quad * 4 + r;
        out[(size_t)m * 1024 + n] = acc[mi][ni][r] + bn;
      }
    }
  }
}

// ---------------------------------------------------------------------------
// Flash attention, BARRIER-FREE. grid = (32,16,2), 256 thr (4 waves).
// Wave = (g in {0,1} q-group of 32 rows) x (hh in {0,1} kv half).
// K/V fragments loaded straight from global (L2-resident per XCD).
// Swapped QK^T (S^T = K·Q^T), accumulator seeded from precomputed log2-domain
// mask table, bare exp2, cvt-pack + permlane32_swap -> PV A-frags.
// End: halves merged through 16 KB LDS (single barrier).
// C/D layout 32x32: col = lane&31, row = (r&3)+8*(r>>2)+4*(lane>>5).
// ---------------------------------------------------------------------------
__global__ __launch_bounds__(256, 4)
void flash_attn(const __bf16* __restrict__ Qg, const __bf16* __restrict__ Kg,
                const __bf16* __restrict__ VTg, const float* __restrict__ maskf,
                __bf16* __restrict__ ctx) {
  __shared__ __align__(16) float Om[2][32][64];   // [g][qrow][d]
  __shared__ float Lm[2][32];

  const int t    = threadIdx.x;
  const int lane = t & 63;
  const int w    = t >> 6;
  const int g    = w & 1;    // q-group (32 rows)
  const int hh   = w >> 1;   // kv half
  const int n32  = lane & 31;
  const int h    = lane >> 5;

  // XCD swizzle: 1024 blocks = 8 XCDs x 128 -> 4 heads per XCD (KV 2MB in L2)
  const int linear = blockIdx.x + (blockIdx.y << 5) + (blockIdx.z << 9);
  const int sw     = (linear & 7) * 128 + (linear >> 3);
  const int qt     = sw & 31;
  const int head   = (sw >> 5) & 15;
  const int b      = sw >> 9;

  const size_t bh = (size_t)(b * 16 + head);
  const int qbase = qt * 64 + g * 32;

  // Q b-frags (B-operand: lane&31 = q row, d-chunk by lane>>5). Pre-scaled
  // by 0.125*log2e at qkv time -> QK^T lands in the log2 domain.
  bf16_8 bq[4];
  {
    const __bf16* qptr = Qg + (bh * 2048 + qbase + n32) * 64 + h * 8;
#pragma unroll
    for (int s = 0; s < 4; ++s) bq[s] = *(const bf16_8*)(qptr + s * 16);
  }

  const f32x16 z16 = {0.f,0.f,0.f,0.f,0.f,0.f,0.f,0.f,
                      0.f,0.f,0.f,0.f,0.f,0.f,0.f,0.f};
  f32x16 o0 = z16, o1 = z16;   // O[32q x 64d]: d-halves
  float lsum = 0.f;

  // walking pointers for this wave's kv half
  const __bf16* kS  = Kg  + (bh * 2048 + hh * 1024 + n32) * 64 + h * 8;
  const __bf16* vS0 = VTg + (bh * 64 + n32) * 2048 + hh * 1024 + h * 8;
  const __bf16* vS1 = vS0 + 32 * 2048;
  const float*  mS  = maskf + b * 2048 + hh * 1024 + 4 * h;

#pragma unroll 2
  for (int it = 0; it < 32; ++it) {
    // S^T = K · Q^T, accumulator SEEDED with the log2-domain mask additive:
    // p[4j+e] needs maskadd[k0 + e + 8j + 4h] (k_local = (r&3)+8*(r>>2)+4h)
    f32x16 p;
#pragma unroll
    for (int j = 0; j < 4; ++j) {
      const f32x4 m4 = *(const f32x4*)(mS + 8 * j);
      p[4 * j + 0] = m4[0];
      p[4 * j + 1] = m4[1];
      p[4 * j + 2] = m4[2];
      p[4 * j + 3] = m4[3];
    }
#pragma unroll
    for (int s = 0; s < 4; ++s) {
      const bf16_8 ka = *(const bf16_8*)(kS + s * 16);
      p = MFMA32(ka, bq[s], p);
    }

    // softmax: bare exp2 (Q carried log2e; mask & -12 shift already in p)
    unsigned c[8];
#pragma unroll
    for (int i = 0; i < 8; ++i) {
      const float e0 = __builtin_amdgcn_exp2f(p[2 * i]);
      const float e1 = __builtin_amdgcn_exp2f(p[2 * i + 1]);
      lsum += e0 + e1;
      union { __bf16 hx[2]; unsigned u; } uu;
      uu.hx[0] = (__bf16)e0;
      uu.hx[1] = (__bf16)e1;
      c[i] = uu.u;
    }
    // redistribute to PV A-frag layout
    asm volatile("v_permlane32_swap_b32 %0, %1" : "+v"(c[0]), "+v"(c[2]));
    asm volatile("v_permlane32_swap_b32 %0, %1" : "+v"(c[1]), "+v"(c[3]));
    asm volatile("v_permlane32_swap_b32 %0, %1" : "+v"(c[4]), "+v"(c[6]));
    asm volatile("v_permlane32_swap_b32 %0, %1" : "+v"(c[5]), "+v"(c[7]));

#pragma unroll
    for (int sub = 0; sub < 2; ++sub) {
      const u32x4 av = {c[4 * sub + 0], c[4 * sub + 1],
                        c[4 * sub + 2], c[4 * sub + 3]};
      const bf16_8 aP = __builtin_bit_cast(bf16_8, av);
      const bf16_8 vb0 = *(const bf16_8*)(vS0 + sub * 16);
      const bf16_8 vb1 = *(const bf16_8*)(vS1 + sub * 16);
      o0 = MFMA32(aP, vb0, o0);
      o1 = MFMA32(aP, vb1, o1);
    }

    kS  += 32 * 64;  // next 32 k-rows
    vS0 += 32;       // next 32 kv columns
    vS1 += 32;
    mS  += 32;
  }

  // full row-sum over this wave's kv-half (lane's two k subsets are disjoint)
  lsum += __shfl_xor(lsum, 32);

  if (hh) {  // upper half: publish partials
#pragma unroll
    for (int r = 0; r < 16; ++r) {
      const int qrow = (r & 3) + 8 * (r >> 2) + 4 * h;
      Om[g][qrow][n32]      = o0[r];
      Om[g][qrow][32 + n32] = o1[r];
    }
    if (h == 0) Lm[g][n32] = lsum;
  }
  __syncthreads();
  if (!hh) {  // lower half: merge, normalize, store
    const float linv = 1.0f / (lsum + Lm[g][n32]);
#pragma unroll
    for (int r = 0; r < 16; ++r) {
      const int qrow = (r & 3) + 8 * (r >> 2) + 4 * h;
      const float li = __shfl(linv, qrow);
      __bf16* cp = ctx + ((size_t)b * 2048 + qbase + qrow) * 1024 + head * 64;
      cp[n32]      = (__bf16)((o0[r] + Om[g][qrow][n32]) * li);
      cp[32 + n32] = (__bf16)((o1[r] + Om[g][qrow][32 + n32]) * li);
    }
  }
}

// ---------------------------------------------------------------------------
// merged f32 -> bf16 converter + mask-additive table build (log2 domain)
// ---------------------------------------------------------------------------
__global__ __launch_bounds__(256)
void cvt_all(const float* __restrict__ q, const float* __restrict__ k,
             const float* __restrict__ v, const float* __restrict__ Wq,
             const float* __restrict__ Wk, const float* __restrict__ Wv,
             const float* __restrict__ Wo, const int* __restrict__ mask,
             __bf16* __restrict__ xq, __bf16* __restrict__ xk,
             __bf16* __restrict__ xv, __bf16* __restrict__ wqb,
             __bf16* __restrict__ wkb, __bf16* __restrict__ wvb,
             __bf16* __restrict__ wob, float* __restrict__ maskf) {
  const int y = blockIdx.y;
  const int i = blockIdx.x * blockDim.x + threadIdx.x;
  if (y == 7) {  // mask -> log2-domain additive (-12*log2e valid, -1e30 masked)
    if (i < 4096) maskf[i] = mask[i] ? -17.3123404907f : -1e30f;
    return;
  }
  const float* s;
  __bf16* d;
  int n8;
  switch (y) {
    case 0: s = q;  d = xq;  n8 = 524288; break;
    case 1: s = k;  d = xk;  n8 = 524288; break;
    case 2: s = v;  d = xv;  n8 = 524288; break;
    case 3: s = Wq; d = wqb; n8 = 131072; break;
    case 4: s = Wk; d = wkb; n8 = 131072; break;
    case 5: s = Wv; d = wvb; n8 = 131072; break;
    default: s = Wo; d = wob; n8 = 131072; break;
  }
  if (i < n8) {
    const float4* sp = (const float4*)s;
    const float4 v0 = sp[i * 2], v1 = sp[i * 2 + 1];
    bf16_8 o;
    o[0] = (__bf16)v0.x; o[1] = (__bf16)v0.y;
    o[2] = (__bf16)v0.z; o[3] = (__bf16)v0.w;
    o[4] = (__bf16)v1.x; o[5] = (__bf16)v1.y;
    o[6] = (__bf16)v1.z; o[7] = (__bf16)v1.w;
    *(bf16_8*)(d + (size_t)i * 8) = o;
  }
}

// ---------------------------------------------------------------------------
extern "C" void kernel_launch(void* const* d_in, const int* in_sizes, int n_in,
                              void* d_out, int out_size, void* d_ws, size_t ws_size,
                              hipStream_t stream) {
  (void)in_sizes; (void)n_in; (void)out_size; (void)ws_size;
  const float* q    = (const float*)d_in[0];
  const float* k    = (const float*)d_in[1];
  const float* v    = (const float*)d_in[2];
  const int*   mask = (const int*)d_in[3];
  const float* Wq = (const float*)d_in[4];
  const float* bq = (const float*)d_in[5];
  const float* Wk = (const float*)d_in[6];
  const float* bk = (const float*)d_in[7];
  const float* Wv = (const float*)d_in[8];
  const float* bv = (const float*)d_in[9];
  const float* Wo = (const float*)d_in[10];
  const float* bo = (const float*)d_in[11];

  char* ws = (char*)d_ws;
  const size_t MB = 1ull << 20;
  __bf16* xq  = (__bf16*)(ws + 0 * MB);
  __bf16* xk  = (__bf16*)(ws + 8 * MB);
  __bf16* xv  = (__bf16*)(ws + 16 * MB);
  __bf16* wqb = (__bf16*)(ws + 24 * MB);
  __bf16* wkb = (__bf16*)(ws + 26 * MB);
  __bf16* wvb = (__bf16*)(ws + 28 * MB);
  __bf16* wob = (__bf16*)(ws + 30 * MB);
  __bf16* Qb  = (__bf16*)(ws + 32 * MB);
  __bf16* Kb  = (__bf16*)(ws + 40 * MB);
  __bf16* VTb = (__bf16*)(ws + 48 * MB);
  __bf16* ctx = (__bf16*)(ws + 56 * MB);
  float*  maskf = (float*)(ws + 70 * MB);

  cvt_all<<<dim3(2048, 8), 256, 0, stream>>>(q, k, v, Wq, Wk, Wv, Wo, mask,
                                             xq, xk, xv, wqb, wkb, wvb, wob,
                                             maskf);

  qkv_fused<<<dim3(256, 1, 3), 256, 0, stream>>>(xq, xk, xv, wqb, wkb, wvb,
                                                 bq, bk, bv, Qb, Kb, VTb);

  flash_attn<<<dim3(32, 16, 2), 256, 0, stream>>>(Qb, Kb, VTb, maskf, ctx);

  out_proj<<<dim3(512), 256, 0, stream>>>(ctx, wob, bo, (float*)d_out);
}

// Round 6
// 228.286 us; speedup vs baseline: 1.3426x; 1.3426x over previous
//
#include <hip/hip_runtime.h>

// ---------------------------------------------------------------------------
// MultiHeadAttention (B=2, S=2048, D=1024, H=16, dk=64) on gfx950
// R10 = R5 VERBATIM (passing, 221.4 us) with EXACTLY ONE change:
//   out_proj moved from 64x128 tiles (512 blocks) to the verified 128x128
//   gemm_core_128 (256 blocks). Bisection round for R9's correctness failure:
//   flash/qkv/cvt are byte-identical to the R5 passing kernel, so a failure
//   here indicts out_proj-128^2; a pass indicts R9's flash prefetch combo.
// ---------------------------------------------------------------------------

typedef __bf16 bf16_8 __attribute__((ext_vector_type(8)));
typedef float  f32x4  __attribute__((ext_vector_type(4)));
typedef float  f32x16 __attribute__((ext_vector_type(16)));
typedef unsigned int u32x4 __attribute__((ext_vector_type(4)));

#define MFMA16(a, b, c) __builtin_amdgcn_mfma_f32_16x16x32_bf16((a), (b), (c), 0, 0, 0)
#define MFMA32(a, b, c) __builtin_amdgcn_mfma_f32_32x32x16_bf16((a), (b), (c), 0, 0, 0)

__device__ __forceinline__ void async_ld16(const void* g, void* l) {
  __builtin_amdgcn_global_load_lds(
      (__attribute__((address_space(1))) void*)g,
      (__attribute__((address_space(3))) void*)l, 16, 0, 0);
}

// ---------------------------------------------------------------------------
// 128x128 GEMM core (m97 structure), BK=32, A [MxK] rm, BT [NxK] rm.
// ---------------------------------------------------------------------------
__device__ __forceinline__ void gemm_core_128(
    const __bf16* __restrict__ A, const __bf16* __restrict__ BT, int K,
    int tm, int tn, __bf16* At, __bf16* Bt, f32x4 acc[4][4]) {
  const int tid  = threadIdx.x;
  const int lane = tid & 63;
  const int w    = tid >> 6;
  const int quad = lane >> 4;
  const int c16  = lane & 15;
  const int wm = w >> 1, wn = w & 1;

  const int ch0  = w * 2;
  const int row0 = ch0 * 16 + (lane >> 2);
  const int col0 = (lane & 3) * 8;
  const __bf16* Ag = A  + (size_t)(tm + row0) * K + col0;
  const __bf16* Bg = BT + (size_t)(tn + row0) * K + col0;
  __bf16* Al = At + ch0 * 512;
  __bf16* Bl = Bt + ch0 * 512;
  const size_t rowK16 = (size_t)16 * K;

  for (int kt = 0; kt < K; kt += 32) {
    async_ld16(Ag + kt,          Al);
    async_ld16(Ag + rowK16 + kt, Al + 512);
    async_ld16(Bg + kt,          Bl);
    async_ld16(Bg + rowK16 + kt, Bl + 512);
    __syncthreads();

    bf16_8 af[4], bfr[4];
#pragma unroll
    for (int mi = 0; mi < 4; ++mi)
      af[mi] = *(const bf16_8*)(At + (wm * 64 + mi * 16 + c16) * 32 + quad * 8);
#pragma unroll
    for (int ni = 0; ni < 4; ++ni)
      bfr[ni] = *(const bf16_8*)(Bt + (wn * 64 + ni * 16 + c16) * 32 + quad * 8);
#pragma unroll
    for (int mi = 0; mi < 4; ++mi)
#pragma unroll
      for (int ni = 0; ni < 4; ++ni)
        acc[mi][ni] = MFMA16(af[mi], bfr[ni], acc[mi][ni]);
    __syncthreads();
  }
}

// ---------------------------------------------------------------------------
// Fused QKV projection. grid = (256,1,3). V produced transposed [B,H,64,S].
// Q output pre-scaled by 1/sqrt(dk)=0.125 (flash consumes it directly).
// ---------------------------------------------------------------------------
__global__ __launch_bounds__(256)
void qkv_fused(const __bf16* __restrict__ xq, const __bf16* __restrict__ xk,
               const __bf16* __restrict__ xv,
               const __bf16* __restrict__ wq, const __bf16* __restrict__ wk,
               const __bf16* __restrict__ wv,
               const float* __restrict__ bq, const float* __restrict__ bk,
               const float* __restrict__ bv,
               __bf16* __restrict__ Qo, __bf16* __restrict__ Ko,
               __bf16* __restrict__ Vo) {
  __shared__ __bf16 At[128 * 32];
  __shared__ __bf16 Bt[128 * 32];
  const int z  = blockIdx.z;
  const int bx = blockIdx.x;
  const __bf16 *A, *BT;
  const float* bias;
  int tm, tn;
  if (z == 2) {        // V^T: M=1024 feats, N=4096 tokens
    A = wv; BT = xv; bias = bv;
    tm = (bx >> 5) * 128; tn = (bx & 31) * 128;
  } else if (z == 1) {
    A = xk; BT = wk; bias = bk;
    tm = (bx >> 3) * 128; tn = (bx & 7) * 128;
  } else {
    A = xq; BT = wq; bias = bq;
    tm = (bx >> 3) * 128; tn = (bx & 7) * 128;
  }

  f32x4 acc[4][4];
  const f32x4 zero4 = {0.f, 0.f, 0.f, 0.f};
#pragma unroll
  for (int i = 0; i < 4; ++i)
#pragma unroll
    for (int j = 0; j < 4; ++j) acc[i][j] = zero4;

  gemm_core_128(A, BT, 1024, tm, tn, At, Bt, acc);

  const int lane = threadIdx.x & 63;
  const int w    = threadIdx.x >> 6;
  const int quad = lane >> 4, c16 = lane & 15;
  const int wm = w >> 1, wn = w & 1;

  if (z == 2) {
#pragma unroll
    for (int mi = 0; mi < 4; ++mi) {
#pragma unroll
      for (int ni = 0; ni < 4; ++ni) {
        const int n  = tn + wn * 64 + ni * 16 + c16;  // token
        const int bb = n >> 11, s = n & 2047;
#pragma unroll
        for (int r = 0; r < 4; ++r) {
          const int m  = tm + wm * 64 + mi * 16 + quad * 4 + r;  // feature
          const int hh = m >> 6, d = m & 63;
          Vo[(((size_t)(bb * 16 + hh) * 64 + d) << 11) + s] =
              (__bf16)(acc[mi][ni][r] + bias[m]);
        }
      }
    }
  } else {
    __bf16* Out = (z == 1) ? Ko : Qo;
    const float scale = (z == 0) ? 0.125f : 1.0f;
#pragma unroll
    for (int mi = 0; mi < 4; ++mi) {
#pragma unroll
      for (int ni = 0; ni < 4; ++ni) {
        const int n  = tn + wn * 64 + ni * 16 + c16;  // feature
        const int hh = n >> 6, d = n & 63;
        const float bn = bias[n];
#pragma unroll
        for (int r = 0; r < 4; ++r) {
          const int m  = tm + wm * 64 + mi * 16 + quad * 4 + r;  // token
          const int bb = m >> 11, s = m & 2047;
          Out[(((size_t)(bb * 16 + hh) * 2048 + s) << 6) + d] =
              (__bf16)((acc[mi][ni][r] + bn) * scale);
        }
      }
    }
  }
}

// ---------------------------------------------------------------------------
// Output projection on the 128x128 core. grid = 256 blocks.
// out = ctx @ wo^T + bo, out f32 [4096 x 1024].  (THE ONE CHANGE vs R5.)
// ---------------------------------------------------------------------------
__global__ __launch_bounds__(256)
void out_proj(const __bf16* __restrict__ ctx, const __bf16* __restrict__ wo,
              const float* __restrict__ bo, float* __restrict__ out) {
  __shared__ __bf16 At[128 * 32];
  __shared__ __bf16 Bt[128 * 32];
  const int bx = blockIdx.x;
  const int tm = (bx >> 3) * 128, tn = (bx & 7) * 128;

  f32x4 acc[4][4];
  const f32x4 zero4 = {0.f, 0.f, 0.f, 0.f};
#pragma unroll
  for (int i = 0; i < 4; ++i)
#pragma unroll
    for (int j = 0; j < 4; ++j) acc[i][j] = zero4;

  gemm_core_128(ctx, wo, 1024, tm, tn, At, Bt, acc);

  const int lane = threadIdx.x & 63;
  const int w    = threadIdx.x >> 6;
  const int quad = lane >> 4, c16 = lane & 15;
  const int wm = w >> 1, wn = w & 1;

#pragma unroll
  for (int mi = 0; mi < 4; ++mi) {
#pragma unroll
    for (int ni = 0; ni < 4; ++ni) {
      const int n = tn + wn * 64 + ni * 16 + c16;
      const float bn = bo[n];
#pragma unroll
      for (int r = 0; r < 4; ++r) {
        const int m = tm + wm * 64 + mi * 16 + quad * 4 + r;
        out[(size_t)m * 1024 + n] = acc[mi][ni][r] + bn;
      }
    }
  }
}

// ---------------------------------------------------------------------------
// Flash attention, 32x32 MFMA, swapped QK^T, in-register softmax.
// grid = (16,16,2), 512 thr (8 waves). Waves 0-3: q-groups x KV[0:1024);
// waves 4-7: same q-groups x KV[1024:2048). End merge through LDS.
// Fixed-shift log2-domain softmax (ma folds mask & -12 shift) => halves
// combine by simple addition (no running max).
// C/D layout 32x32: col = lane&31, row = (r&3)+8*(r>>2)+4*(lane>>5).
// (VERBATIM R5 — the 55.1 us passing version.)
// ---------------------------------------------------------------------------
__global__ __launch_bounds__(512, 4)
void flash_attn(const __bf16* __restrict__ Qg, const __bf16* __restrict__ Kg,
                const __bf16* __restrict__ VTg, const int* __restrict__ maskg,
                __bf16* __restrict__ ctx) {
  __shared__ __align__(16) __bf16 Kl[2][64 * 72];   // [kv-half][64 k x 64 d]
  __shared__ __align__(16) __bf16 Vl[2][64 * 72];   // [kv-half][64 d x 64 k]
  __shared__ __align__(16) float  maskadd[2][64];
  __shared__ __align__(16) float  Om[4][32][64];    // upper-half partial O
  __shared__ float Lm[4][32];                       // upper-half partial l

  const int t    = threadIdx.x;
  const int lane = t & 63;
  const int w    = t >> 6;
  const int g    = w & 3;    // q-group (32 rows)
  const int hh   = w >> 2;   // kv half
  const int n32  = lane & 31;
  const int h    = lane >> 5;

  // XCD swizzle: 512 blocks = 8 XCDs x 64; chunk so one XCD sees 4 heads' KV.
  const int linear = blockIdx.x + (blockIdx.y << 4) + (blockIdx.z << 8);
  const int sw     = (linear & 7) * 64 + (linear >> 3);
  const int qt     = sw & 15;
  const int head   = (sw >> 4) & 15;
  const int b      = sw >> 8;

  const size_t bh = (size_t)(b * 16 + head);
  const int qbase = qt * 128 + g * 32;

  // Q b-frags (B-operand: lane&31 = q row, k-chunk by lane>>5). Pre-scaled.
  bf16_8 bq[4];
  {
    const __bf16* qptr = Qg + (bh * 2048 + qbase + n32) * 64 + h * 8;
#pragma unroll
    for (int s = 0; s < 4; ++s) bq[s] = *(const bf16_8*)(qptr + s * 16);
  }

  const f32x16 z16 = {0.f,0.f,0.f,0.f,0.f,0.f,0.f,0.f,
                      0.f,0.f,0.f,0.f,0.f,0.f,0.f,0.f};
  f32x16 o0 = z16, o1 = z16;   // O[32q x 64d]: dt=0,1
  float lsum = 0.f;

  // staging: threads 0-255 stage half 0, 256-511 half 1 (hh == t>>8)
  const int tl   = t & 255;
  const int srow = tl >> 2, scc = (tl & 3) * 16;
  const __bf16* Kgp = Kg  + (bh * 2048 + hh * 1024) * 64;
  const __bf16* Vgp = VTg + bh * 64 * 2048 + hh * 1024;
  const int*    mgp = maskg + b * 2048 + hh * 1024;
  const float LOG2E = 1.44269504088896f;

  for (int kt = 0; kt < 1024; kt += 64) {
    {
      const size_t kb = (size_t)(kt + srow) * 64 + scc;
      *(bf16_8*)&Kl[hh][srow * 72 + scc]     = *(const bf16_8*)&Kgp[kb];
      *(bf16_8*)&Kl[hh][srow * 72 + scc + 8] = *(const bf16_8*)&Kgp[kb + 8];
      const size_t vbi = (size_t)srow * 2048 + kt + scc;
      *(bf16_8*)&Vl[hh][srow * 72 + scc]     = *(const bf16_8*)&Vgp[vbi];
      *(bf16_8*)&Vl[hh][srow * 72 + scc + 8] = *(const bf16_8*)&Vgp[vbi + 8];
      if (tl < 64) maskadd[hh][tl] = mgp[kt + tl] ? -17.3123404907f : -1e30f;
    }
    __syncthreads();

#pragma unroll
    for (int kt2 = 0; kt2 < 2; ++kt2) {
      // S^T = K · Q^T : lane (q=n32, h) reg r holds k_local=(r&3)+8*(r>>2)+4h
      f32x16 p = z16;
#pragma unroll
      for (int s = 0; s < 4; ++s) {
        const bf16_8 ka =
            *(const bf16_8*)&Kl[hh][(kt2 * 32 + n32) * 72 + s * 16 + h * 8];
        p = MFMA32(ka, bq[s], p);
      }
      // in-register softmax (log2 domain) + pack to bf16 pairs
      unsigned c[8];
#pragma unroll
      for (int i = 0; i < 8; ++i) {
        const int r0 = 2 * i, r1 = 2 * i + 1;
        const float ma0 =
            maskadd[hh][kt2 * 32 + (r0 & 3) + 8 * (r0 >> 2) + 4 * h];
        const float ma1 =
            maskadd[hh][kt2 * 32 + (r1 & 3) + 8 * (r1 >> 2) + 4 * h];
        const float e0 = __builtin_amdgcn_exp2f(fmaf(p[r0], LOG2E, ma0));
        const float e1 = __builtin_amdgcn_exp2f(fmaf(p[r1], LOG2E, ma1));
        lsum += e0 + e1;
        union { __bf16 hx[2]; unsigned u; } uu;
        uu.hx[0] = (__bf16)e0;
        uu.hx[1] = (__bf16)e1;
        c[i] = uu.u;
      }
      // redistribute to PV A-frag layout
      asm volatile("v_permlane32_swap_b32 %0, %1" : "+v"(c[0]), "+v"(c[2]));
      asm volatile("v_permlane32_swap_b32 %0, %1" : "+v"(c[1]), "+v"(c[3]));
      asm volatile("v_permlane32_swap_b32 %0, %1" : "+v"(c[4]), "+v"(c[6]));
      asm volatile("v_permlane32_swap_b32 %0, %1" : "+v"(c[5]), "+v"(c[7]));
#pragma unroll
      for (int sub = 0; sub < 2; ++sub) {
        const u32x4 av = {c[4 * sub + 0], c[4 * sub + 1],
                          c[4 * sub + 2], c[4 * sub + 3]};
        const bf16_8 aP = __builtin_bit_cast(bf16_8, av);
        const int s = kt2 * 2 + sub;
        const bf16_8 vb0 =
            *(const bf16_8*)&Vl[hh][n32 * 72 + s * 16 + h * 8];
        const bf16_8 vb1 =
            *(const bf16_8*)&Vl[hh][(32 + n32) * 72 + s * 16 + h * 8];
        o0 = MFMA32(aP, vb0, o0);
        o1 = MFMA32(aP, vb1, o1);
      }
    }
    __syncthreads();
  }

  // full row-sum over this wave's kv-half (lane's two k subsets are disjoint)
  lsum += __shfl_xor(lsum, 32);

  if (hh) {  // upper half: publish partials
#pragma unroll
    for (int r = 0; r < 16; ++r) {
      const int qrow = (r & 3) + 8 * (r >> 2) + 4 * h;
      Om[g][qrow][n32]      = o0[r];
      Om[g][qrow][32 + n32] = o1[r];
    }
    if (h == 0) Lm[g][n32] = lsum;
  }
  __syncthreads();
  if (!hh) {  // lower half: merge, normalize, store
    const float linv = 1.0f / (lsum + Lm[g][n32]);
#pragma unroll
    for (int r = 0; r < 16; ++r) {
      const int qrow = (r & 3) + 8 * (r >> 2) + 4 * h;
      const float li = __shfl(linv, qrow);
      __bf16* cp = ctx + ((size_t)b * 2048 + qbase + qrow) * 1024 + head * 64;
      cp[n32]      = (__bf16)((o0[r] + Om[g][qrow][n32]) * li);
      cp[32 + n32] = (__bf16)((o1[r] + Om[g][qrow][32 + n32]) * li);
    }
  }
}

// ---------------------------------------------------------------------------
// merged f32 -> bf16 converter
// ---------------------------------------------------------------------------
__global__ __launch_bounds__(256)
void cvt_all(const float* __restrict__ q, const float* __restrict__ k,
             const float* __restrict__ v, const float* __restrict__ Wq,
             const float* __restrict__ Wk, const float* __restrict__ Wv,
             const float* __restrict__ Wo,
             __bf16* __restrict__ xq, __bf16* __restrict__ xk,
             __bf16* __restrict__ xv, __bf16* __restrict__ wqb,
             __bf16* __restrict__ wkb, __bf16* __restrict__ wvb,
             __bf16* __restrict__ wob) {
  const int y = blockIdx.y;
  const float* s;
  __bf16* d;
  int n8;
  switch (y) {
    case 0: s = q;  d = xq;  n8 = 524288; break;
    case 1: s = k;  d = xk;  n8 = 524288; break;
    case 2: s = v;  d = xv;  n8 = 524288; break;
    case 3: s = Wq; d = wqb; n8 = 131072; break;
    case 4: s = Wk; d = wkb; n8 = 131072; break;
    case 5: s = Wv; d = wvb; n8 = 131072; break;
    default: s = Wo; d = wob; n8 = 131072; break;
  }
  const int i = blockIdx.x * blockDim.x + threadIdx.x;
  if (i < n8) {
    const float4* sp = (const float4*)s;
    const float4 v0 = sp[i * 2], v1 = sp[i * 2 + 1];
    bf16_8 o;
    o[0] = (__bf16)v0.x; o[1] = (__bf16)v0.y;
    o[2] = (__bf16)v0.z; o[3] = (__bf16)v0.w;
    o[4] = (__bf16)v1.x; o[5] = (__bf16)v1.y;
    o[6] = (__bf16)v1.z; o[7] = (__bf16)v1.w;
    *(bf16_8*)(d + (size_t)i * 8) = o;
  }
}

// ---------------------------------------------------------------------------
extern "C" void kernel_launch(void* const* d_in, const int* in_sizes, int n_in,
                              void* d_out, int out_size, void* d_ws, size_t ws_size,
                              hipStream_t stream) {
  (void)in_sizes; (void)n_in; (void)out_size; (void)ws_size;
  const float* q    = (const float*)d_in[0];
  const float* k    = (const float*)d_in[1];
  const float* v    = (const float*)d_in[2];
  const int*   mask = (const int*)d_in[3];
  const float* Wq = (const float*)d_in[4];
  const float* bq = (const float*)d_in[5];
  const float* Wk = (const float*)d_in[6];
  const float* bk = (const float*)d_in[7];
  const float* Wv = (const float*)d_in[8];
  const float* bv = (const float*)d_in[9];
  const float* Wo = (const float*)d_in[10];
  const float* bo = (const float*)d_in[11];

  char* ws = (char*)d_ws;
  const size_t MB = 1ull << 20;
  __bf16* xq  = (__bf16*)(ws + 0 * MB);
  __bf16* xk  = (__bf16*)(ws + 8 * MB);
  __bf16* xv  = (__bf16*)(ws + 16 * MB);
  __bf16* wqb = (__bf16*)(ws + 24 * MB);
  __bf16* wkb = (__bf16*)(ws + 26 * MB);
  __bf16* wvb = (__bf16*)(ws + 28 * MB);
  __bf16* wob = (__bf16*)(ws + 30 * MB);
  __bf16* Qb  = (__bf16*)(ws + 32 * MB);
  __bf16* Kb  = (__bf16*)(ws + 40 * MB);
  __bf16* VTb = (__bf16*)(ws + 48 * MB);
  __bf16* ctx = (__bf16*)(ws + 56 * MB);

  cvt_all<<<dim3(2048, 7), 256, 0, stream>>>(q, k, v, Wq, Wk, Wv, Wo,
                                             xq, xk, xv, wqb, wkb, wvb, wob);

  qkv_fused<<<dim3(256, 1, 3), 256, 0, stream>>>(xq, xk, xv, wqb, wkb, wvb,
                                                 bq, bk, bv, Qb, Kb, VTb);

  flash_attn<<<dim3(16, 16, 2), 512, 0, stream>>>(Qb, Kb, VTb, mask, ctx);

  out_proj<<<dim3(256), 256, 0, stream>>>(ctx, wob, bo, (float*)d_out);
}

// Round 7
// 220.858 us; speedup vs baseline: 1.3877x; 1.0336x over previous
//
#include <hip/hip_runtime.h>

// ---------------------------------------------------------------------------
// MultiHeadAttention (B=2, S=2048, D=1024, H=16, dk=64) on gfx950
// R11 = R5 base with:
//  - out_proj: R5's 64x128/512-block version (R10 bisect: 128^2@256blk −7us)
//  - flash: KVBLK=128 (8 iters, HALF the barriers; was 16x64), same verified
//    2-barrier single-buffer sync. LDS 71.5 KB, still 2 blocks/CU.
//  - flash softmax: R7-verified seed/exp2 (Q pre-scaled 0.125*log2e at qkv;
//    p seeded from mask-additive vectors; bare exp2). No ones-MFMA (R7 regression),
//    no register prefetch (R9's trip-count bug taught: one delta at a time).
// R9's failure root-cause: loop bound 2048 with per-half pointers (read past
// head range + double-counted keys). Fixed by construction here (ktb < 1024).
// ---------------------------------------------------------------------------

typedef __bf16 bf16_8 __attribute__((ext_vector_type(8)));
typedef float  f32x4  __attribute__((ext_vector_type(4)));
typedef float  f32x16 __attribute__((ext_vector_type(16)));
typedef unsigned int u32x4 __attribute__((ext_vector_type(4)));

#define MFMA16(a, b, c) __builtin_amdgcn_mfma_f32_16x16x32_bf16((a), (b), (c), 0, 0, 0)
#define MFMA32(a, b, c) __builtin_amdgcn_mfma_f32_32x32x16_bf16((a), (b), (c), 0, 0, 0)

__device__ __forceinline__ void async_ld16(const void* g, void* l) {
  __builtin_amdgcn_global_load_lds(
      (__attribute__((address_space(1))) void*)g,
      (__attribute__((address_space(3))) void*)l, 16, 0, 0);
}

// ---------------------------------------------------------------------------
// 128x128 GEMM core (m97 structure), BK=32, A [MxK] rm, BT [NxK] rm.
// ---------------------------------------------------------------------------
__device__ __forceinline__ void gemm_core_128(
    const __bf16* __restrict__ A, const __bf16* __restrict__ BT, int K,
    int tm, int tn, __bf16* At, __bf16* Bt, f32x4 acc[4][4]) {
  const int tid  = threadIdx.x;
  const int lane = tid & 63;
  const int w    = tid >> 6;
  const int quad = lane >> 4;
  const int c16  = lane & 15;
  const int wm = w >> 1, wn = w & 1;

  const int ch0  = w * 2;
  const int row0 = ch0 * 16 + (lane >> 2);
  const int col0 = (lane & 3) * 8;
  const __bf16* Ag = A  + (size_t)(tm + row0) * K + col0;
  const __bf16* Bg = BT + (size_t)(tn + row0) * K + col0;
  __bf16* Al = At + ch0 * 512;
  __bf16* Bl = Bt + ch0 * 512;
  const size_t rowK16 = (size_t)16 * K;

  for (int kt = 0; kt < K; kt += 32) {
    async_ld16(Ag + kt,          Al);
    async_ld16(Ag + rowK16 + kt, Al + 512);
    async_ld16(Bg + kt,          Bl);
    async_ld16(Bg + rowK16 + kt, Bl + 512);
    __syncthreads();

    bf16_8 af[4], bfr[4];
#pragma unroll
    for (int mi = 0; mi < 4; ++mi)
      af[mi] = *(const bf16_8*)(At + (wm * 64 + mi * 16 + c16) * 32 + quad * 8);
#pragma unroll
    for (int ni = 0; ni < 4; ++ni)
      bfr[ni] = *(const bf16_8*)(Bt + (wn * 64 + ni * 16 + c16) * 32 + quad * 8);
#pragma unroll
    for (int mi = 0; mi < 4; ++mi)
#pragma unroll
      for (int ni = 0; ni < 4; ++ni)
        acc[mi][ni] = MFMA16(af[mi], bfr[ni], acc[mi][ni]);
    __syncthreads();
  }
}

// ---------------------------------------------------------------------------
// Fused QKV projection. grid = (256,1,3). V produced transposed [B,H,64,S].
// Q output pre-scaled by 0.125*log2e (flash softmax works in log2 domain).
// ---------------------------------------------------------------------------
__global__ __launch_bounds__(256)
void qkv_fused(const __bf16* __restrict__ xq, const __bf16* __restrict__ xk,
               const __bf16* __restrict__ xv,
               const __bf16* __restrict__ wq, const __bf16* __restrict__ wk,
               const __bf16* __restrict__ wv,
               const float* __restrict__ bq, const float* __restrict__ bk,
               const float* __restrict__ bv,
               __bf16* __restrict__ Qo, __bf16* __restrict__ Ko,
               __bf16* __restrict__ Vo) {
  __shared__ __bf16 At[128 * 32];
  __shared__ __bf16 Bt[128 * 32];
  const int z  = blockIdx.z;
  const int bx = blockIdx.x;
  const __bf16 *A, *BT;
  const float* bias;
  int tm, tn;
  if (z == 2) {        // V^T: M=1024 feats, N=4096 tokens
    A = wv; BT = xv; bias = bv;
    tm = (bx >> 5) * 128; tn = (bx & 31) * 128;
  } else if (z == 1) {
    A = xk; BT = wk; bias = bk;
    tm = (bx >> 3) * 128; tn = (bx & 7) * 128;
  } else {
    A = xq; BT = wq; bias = bq;
    tm = (bx >> 3) * 128; tn = (bx & 7) * 128;
  }

  f32x4 acc[4][4];
  const f32x4 zero4 = {0.f, 0.f, 0.f, 0.f};
#pragma unroll
  for (int i = 0; i < 4; ++i)
#pragma unroll
    for (int j = 0; j < 4; ++j) acc[i][j] = zero4;

  gemm_core_128(A, BT, 1024, tm, tn, At, Bt, acc);

  const int lane = threadIdx.x & 63;
  const int w    = threadIdx.x >> 6;
  const int quad = lane >> 4, c16 = lane & 15;
  const int wm = w >> 1, wn = w & 1;

  if (z == 2) {
#pragma unroll
    for (int mi = 0; mi < 4; ++mi) {
#pragma unroll
      for (int ni = 0; ni < 4; ++ni) {
        const int n  = tn + wn * 64 + ni * 16 + c16;  // token
        const int bb = n >> 11, s = n & 2047;
#pragma unroll
        for (int r = 0; r < 4; ++r) {
          const int m  = tm + wm * 64 + mi * 16 + quad * 4 + r;  // feature
          const int hh = m >> 6, d = m & 63;
          Vo[(((size_t)(bb * 16 + hh) * 64 + d) << 11) + s] =
              (__bf16)(acc[mi][ni][r] + bias[m]);
        }
      }
    }
  } else {
    __bf16* Out = (z == 1) ? Ko : Qo;
    const float scale = (z == 0) ? 0.1803368801f : 1.0f;  // 0.125 * log2(e)
#pragma unroll
    for (int mi = 0; mi < 4; ++mi) {
#pragma unroll
      for (int ni = 0; ni < 4; ++ni) {
        const int n  = tn + wn * 64 + ni * 16 + c16;  // feature
        const int hh = n >> 6, d = n & 63;
        const float bn = bias[n];
#pragma unroll
        for (int r = 0; r < 4; ++r) {
          const int m  = tm + wm * 64 + mi * 16 + quad * 4 + r;  // token
          const int bb = m >> 11, s = m & 2047;
          Out[(((size_t)(bb * 16 + hh) * 2048 + s) << 6) + d] =
              (__bf16)((acc[mi][ni][r] + bn) * scale);
        }
      }
    }
  }
}

// ---------------------------------------------------------------------------
// Output projection, 64x128 tile -> 512 blocks (2 blocks/CU). (R5 version.)
// ---------------------------------------------------------------------------
__global__ __launch_bounds__(256)
void out_proj(const __bf16* __restrict__ ctx, const __bf16* __restrict__ wo,
              const float* __restrict__ bo, float* __restrict__ out) {
  __shared__ __bf16 At[64 * 32];
  __shared__ __bf16 Bt[128 * 32];
  const int bx = blockIdx.x;
  const int tm = (bx >> 3) * 64, tn = (bx & 7) * 128;

  const int tid  = threadIdx.x;
  const int lane = tid & 63, w = tid >> 6;
  const int quad = lane >> 4, c16 = lane & 15;
  const int wm = w >> 1, wn = w & 1;

  const int row0 = lane >> 2, col0 = (lane & 3) * 8;
  const __bf16* Ag = ctx + (size_t)(tm + w * 16 + row0) * 1024 + col0;
  const __bf16* Bg = wo  + (size_t)(tn + w * 32 + row0) * 1024 + col0;
  __bf16* Al = At + w * 512;
  __bf16* Bl = Bt + w * 1024;

  f32x4 acc[2][4];
  const f32x4 zero4 = {0.f, 0.f, 0.f, 0.f};
#pragma unroll
  for (int i = 0; i < 2; ++i)
#pragma unroll
    for (int j = 0; j < 4; ++j) acc[i][j] = zero4;

  for (int kt = 0; kt < 1024; kt += 32) {
    async_ld16(Ag + kt, Al);
    async_ld16(Bg + kt, Bl);
    async_ld16(Bg + 16 * 1024 + kt, Bl + 512);
    __syncthreads();

    bf16_8 af[2], bfr[4];
#pragma unroll
    for (int mi = 0; mi < 2; ++mi)
      af[mi] = *(const bf16_8*)(At + (wm * 32 + mi * 16 + c16) * 32 + quad * 8);
#pragma unroll
    for (int ni = 0; ni < 4; ++ni)
      bfr[ni] = *(const bf16_8*)(Bt + (wn * 64 + ni * 16 + c16) * 32 + quad * 8);
#pragma unroll
    for (int mi = 0; mi < 2; ++mi)
#pragma unroll
      for (int ni = 0; ni < 4; ++ni)
        acc[mi][ni] = MFMA16(af[mi], bfr[ni], acc[mi][ni]);
    __syncthreads();
  }

#pragma unroll
  for (int mi = 0; mi < 2; ++mi) {
#pragma unroll
    for (int ni = 0; ni < 4; ++ni) {
      const int n = tn + wn * 64 + ni * 16 + c16;
      const float bn = bo[n];
#pragma unroll
      for (int r = 0; r < 4; ++r) {
        const int m = tm + wm * 32 + mi * 16 + quad * 4 + r;
        out[(size_t)m * 1024 + n] = acc[mi][ni][r] + bn;
      }
    }
  }
}

// ---------------------------------------------------------------------------
// Flash attention, 32x32 MFMA, swapped QK^T, in-register softmax.
// grid = (16,16,2), 512 thr (8 waves). Waves 0-3: q-groups x KV[0:1024);
// waves 4-7: same q-groups x KV[1024:2048). End merge through LDS.
// R11: KVBLK=128 (8 iters/half, half the barriers of R5). Same 2-barrier
// single-buffer sync. p seeded from mask-additive vectors (log2 domain;
// Q carries 0.125*log2e) -> softmax is bare exp2. Scalar lsum.
// C/D layout 32x32: col = lane&31, row = (r&3)+8*(r>>2)+4*(lane>>5).
// LDS map (bytes):
//   [0,     36864) Kl [half][128 x 72] bf16
//   [36864, 71680) Vl [half][64 x 136] bf16
//   [71680, 72704) maskadd [half][128] f32
//   [72704, 73216) Lm [4][32] f32
//   Om [4][32][64] f32 overlays [0, 32768) after the final barrier.
// ---------------------------------------------------------------------------
__global__ __launch_bounds__(512, 4)
void flash_attn(const __bf16* __restrict__ Qg, const __bf16* __restrict__ Kg,
                const __bf16* __restrict__ VTg, const int* __restrict__ maskg,
                __bf16* __restrict__ ctx) {
  __shared__ __align__(16) char smem_[73216];

  const int t    = threadIdx.x;
  const int lane = t & 63;
  const int w    = t >> 6;
  const int g    = w & 3;    // q-group (32 rows)
  const int hh   = w >> 2;   // kv half
  const int n32  = lane & 31;
  const int h    = lane >> 5;

  // XCD swizzle: 512 blocks = 8 XCDs x 64; chunk so one XCD sees 4 heads' KV.
  const int linear = blockIdx.x + (blockIdx.y << 4) + (blockIdx.z << 8);
  const int sw     = (linear & 7) * 64 + (linear >> 3);
  const int qt     = sw & 15;
  const int head   = (sw >> 4) & 15;
  const int b      = sw >> 8;

  const size_t bh = (size_t)(b * 16 + head);
  const int qbase = qt * 128 + g * 32;

  // Q b-frags (B-operand: lane&31 = q row, k-chunk by lane>>5). Pre-scaled
  // by 0.125*log2e, so QK^T lands directly in the log2 domain.
  bf16_8 bq[4];
  {
    const __bf16* qptr = Qg + (bh * 2048 + qbase + n32) * 64 + h * 8;
#pragma unroll
    for (int s = 0; s < 4; ++s) bq[s] = *(const bf16_8*)(qptr + s * 16);
  }

  const f32x16 z16 = {0.f,0.f,0.f,0.f,0.f,0.f,0.f,0.f,
                      0.f,0.f,0.f,0.f,0.f,0.f,0.f,0.f};
  f32x16 o0 = z16, o1 = z16;   // O[32q x 64d]: dt=0,1
  float lsum = 0.f;

  // per-half LDS views (addresses loop-invariant)
  __bf16* const Kl = (__bf16*)smem_           + hh * (128 * 72);
  __bf16* const Vl = (__bf16*)(smem_ + 36864) + hh * (64 * 136);
  float*  const Ml = (float*)(smem_ + 71680)  + hh * 128;

  // staging: threads 0-255 stage half 0, 256-511 half 1 (hh == t>>8)
  const int tl   = t & 255;
  const int srow = tl >> 2, scc = (tl & 3) * 16;
  const __bf16* Kgp = Kg  + (bh * 2048 + hh * 1024) * 64;
  const __bf16* Vgp = VTg + bh * 64 * 2048 + hh * 1024;
  const int*    mgp = maskg + b * 2048 + hh * 1024;

  for (int ktb = 0; ktb < 1024; ktb += 128) {
    // stage 128 keys: K rows [ktb, ktb+128) and V^T cols [ktb, ktb+128)
#pragma unroll
    for (int r2 = 0; r2 < 2; ++r2) {
      const size_t kb = (size_t)(ktb + r2 * 64 + srow) * 64 + scc;
      __bf16* kw = Kl + (r2 * 64 + srow) * 72 + scc;
      *(bf16_8*)kw       = *(const bf16_8*)&Kgp[kb];
      *(bf16_8*)(kw + 8) = *(const bf16_8*)&Kgp[kb + 8];
      const size_t vb = (size_t)srow * 2048 + ktb + r2 * 64 + scc;
      __bf16* vw = Vl + srow * 136 + r2 * 64 + scc;
      *(bf16_8*)vw       = *(const bf16_8*)&Vgp[vb];
      *(bf16_8*)(vw + 8) = *(const bf16_8*)&Vgp[vb + 8];
    }
    if (tl < 128) Ml[tl] = mgp[ktb + tl] ? -17.3123404907f : -1e30f;
    __syncthreads();

#pragma unroll
    for (int kt2 = 0; kt2 < 4; ++kt2) {
      // S^T = K · Q^T, accumulator SEEDED with the log2-domain mask additive:
      // p[4j+e] needs maskadd[kt2*32 + e + 8j + 4h]
      f32x16 p;
#pragma unroll
      for (int j = 0; j < 4; ++j) {
        const f32x4 m4 = *(const f32x4*)&Ml[kt2 * 32 + 8 * j + 4 * h];
        p[4 * j + 0] = m4[0];
        p[4 * j + 1] = m4[1];
        p[4 * j + 2] = m4[2];
        p[4 * j + 3] = m4[3];
      }
#pragma unroll
      for (int s = 0; s < 4; ++s) {
        const bf16_8 ka =
            *(const bf16_8*)&Kl[(kt2 * 32 + n32) * 72 + s * 16 + h * 8];
        p = MFMA32(ka, bq[s], p);
      }

      // softmax: bare exp2 (Q carried log2e; mask & -12 shift already in p)
      unsigned c[8];
#pragma unroll
      for (int i = 0; i < 8; ++i) {
        const float e0 = __builtin_amdgcn_exp2f(p[2 * i]);
        const float e1 = __builtin_amdgcn_exp2f(p[2 * i + 1]);
        lsum += e0 + e1;
        union { __bf16 hx[2]; unsigned u; } uu;
        uu.hx[0] = (__bf16)e0;
        uu.hx[1] = (__bf16)e1;
        c[i] = uu.u;
      }
      // redistribute to PV A-frag layout
      asm volatile("v_permlane32_swap_b32 %0, %1" : "+v"(c[0]), "+v"(c[2]));
      asm volatile("v_permlane32_swap_b32 %0, %1" : "+v"(c[1]), "+v"(c[3]));
      asm volatile("v_permlane32_swap_b32 %0, %1" : "+v"(c[4]), "+v"(c[6]));
      asm volatile("v_permlane32_swap_b32 %0, %1" : "+v"(c[5]), "+v"(c[7]));

#pragma unroll
      for (int sub = 0; sub < 2; ++sub) {
        const u32x4 av = {c[4 * sub + 0], c[4 * sub + 1],
                          c[4 * sub + 2], c[4 * sub + 3]};
        const bf16_8 aP = __builtin_bit_cast(bf16_8, av);
        const int s = kt2 * 2 + sub;   // k-slot within the 128-key tile
        const bf16_8 vb0 =
            *(const bf16_8*)&Vl[n32 * 136 + s * 16 + h * 8];
        const bf16_8 vb1 =
            *(const bf16_8*)&Vl[(32 + n32) * 136 + s * 16 + h * 8];
        o0 = MFMA32(aP, vb0, o0);
        o1 = MFMA32(aP, vb1, o1);
      }
    }
    __syncthreads();
  }

  // full row-sum over this wave's kv-half (lane's two k subsets are disjoint)
  lsum += __shfl_xor(lsum, 32);

  float (*Om)[32][64] = (float(*)[32][64])smem_;          // overlays staging
  float (*Lm)[32]     = (float(*)[32])(smem_ + 72704);

  if (hh) {  // upper half: publish partials
#pragma unroll
    for (int r = 0; r < 16; ++r) {
      const int qrow = (r & 3) + 8 * (r >> 2) + 4 * h;
      Om[g][qrow][n32]      = o0[r];
      Om[g][qrow][32 + n32] = o1[r];
    }
    if (h == 0) Lm[g][n32] = lsum;
  }
  __syncthreads();
  if (!hh) {  // lower half: merge, normalize, store
    const float linv = 1.0f / (lsum + Lm[g][n32]);
#pragma unroll
    for (int r = 0; r < 16; ++r) {
      const int qrow = (r & 3) + 8 * (r >> 2) + 4 * h;
      const float li = __shfl(linv, qrow);
      __bf16* cp = ctx + ((size_t)b * 2048 + qbase + qrow) * 1024 + head * 64;
      cp[n32]      = (__bf16)((o0[r] + Om[g][qrow][n32]) * li);
      cp[32 + n32] = (__bf16)((o1[r] + Om[g][qrow][32 + n32]) * li);
    }
  }
}

// ---------------------------------------------------------------------------
// merged f32 -> bf16 converter
// ---------------------------------------------------------------------------
__global__ __launch_bounds__(256)
void cvt_all(const float* __restrict__ q, const float* __restrict__ k,
             const float* __restrict__ v, const float* __restrict__ Wq,
             const float* __restrict__ Wk, const float* __restrict__ Wv,
             const float* __restrict__ Wo,
             __bf16* __restrict__ xq, __bf16* __restrict__ xk,
             __bf16* __restrict__ xv, __bf16* __restrict__ wqb,
             __bf16* __restrict__ wkb, __bf16* __restrict__ wvb,
             __bf16* __restrict__ wob) {
  const int y = blockIdx.y;
  const float* s;
  __bf16* d;
  int n8;
  switch (y) {
    case 0: s = q;  d = xq;  n8 = 524288; break;
    case 1: s = k;  d = xk;  n8 = 524288; break;
    case 2: s = v;  d = xv;  n8 = 524288; break;
    case 3: s = Wq; d = wqb; n8 = 131072; break;
    case 4: s = Wk; d = wkb; n8 = 131072; break;
    case 5: s = Wv; d = wvb; n8 = 131072; break;
    default: s = Wo; d = wob; n8 = 131072; break;
  }
  const int i = blockIdx.x * blockDim.x + threadIdx.x;
  if (i < n8) {
    const float4* sp = (const float4*)s;
    const float4 v0 = sp[i * 2], v1 = sp[i * 2 + 1];
    bf16_8 o;
    o[0] = (__bf16)v0.x; o[1] = (__bf16)v0.y;
    o[2] = (__bf16)v0.z; o[3] = (__bf16)v0.w;
    o[4] = (__bf16)v1.x; o[5] = (__bf16)v1.y;
    o[6] = (__bf16)v1.z; o[7] = (__bf16)v1.w;
    *(bf16_8*)(d + (size_t)i * 8) = o;
  }
}

// ---------------------------------------------------------------------------
extern "C" void kernel_launch(void* const* d_in, const int* in_sizes, int n_in,
                              void* d_out, int out_size, void* d_ws, size_t ws_size,
                              hipStream_t stream) {
  (void)in_sizes; (void)n_in; (void)out_size; (void)ws_size;
  const float* q    = (const float*)d_in[0];
  const float* k    = (const float*)d_in[1];
  const float* v    = (const float*)d_in[2];
  const int*   mask = (const int*)d_in[3];
  const float* Wq = (const float*)d_in[4];
  const float* bq = (const float*)d_in[5];
  const float* Wk = (const float*)d_in[6];
  const float* bk = (const float*)d_in[7];
  const float* Wv = (const float*)d_in[8];
  const float* bv = (const float*)d_in[9];
  const float* Wo = (const float*)d_in[10];
  const float* bo = (const float*)d_in[11];

  char* ws = (char*)d_ws;
  const size_t MB = 1ull << 20;
  __bf16* xq  = (__bf16*)(ws + 0 * MB);
  __bf16* xk  = (__bf16*)(ws + 8 * MB);
  __bf16* xv  = (__bf16*)(ws + 16 * MB);
  __bf16* wqb = (__bf16*)(ws + 24 * MB);
  __bf16* wkb = (__bf16*)(ws + 26 * MB);
  __bf16* wvb = (__bf16*)(ws + 28 * MB);
  __bf16* wob = (__bf16*)(ws + 30 * MB);
  __bf16* Qb  = (__bf16*)(ws + 32 * MB);
  __bf16* Kb  = (__bf16*)(ws + 40 * MB);
  __bf16* VTb = (__bf16*)(ws + 48 * MB);
  __bf16* ctx = (__bf16*)(ws + 56 * MB);

  cvt_all<<<dim3(2048, 7), 256, 0, stream>>>(q, k, v, Wq, Wk, Wv, Wo,
                                             xq, xk, xv, wqb, wkb, wvb, wob);

  qkv_fused<<<dim3(256, 1, 3), 256, 0, stream>>>(xq, xk, xv, wqb, wkb, wvb,
                                                 bq, bk, bv, Qb, Kb, VTb);

  flash_attn<<<dim3(16, 16, 2), 512, 0, stream>>>(Qb, Kb, VTb, mask, ctx);

  out_proj<<<dim3(512), 256, 0, stream>>>(ctx, wob, bo, (float*)d_out);
}